// Round 4
// baseline (342.891 us; speedup 1.0000x reference)
//
#include <hip/hip_runtime.h>

typedef unsigned short u16;
typedef u16   u16x4 __attribute__((ext_vector_type(4)));
typedef u16   u16x8 __attribute__((ext_vector_type(8)));
typedef short s16x8 __attribute__((ext_vector_type(8)));
typedef float f32x4 __attribute__((ext_vector_type(4)));

#define NSEQ 256
#define NRES 384
#define NF   64
#define NP   32
#define NO   128

__device__ __forceinline__ u16 f2b(float f) {
    union { float f; unsigned u; } c; c.f = f;
    unsigned r = c.u + 0x7fffu + ((c.u >> 16) & 1u);   // RNE
    return (u16)(r >> 16);
}
__device__ __forceinline__ float b2f(u16 h) {
    union { unsigned u; float f; } c; c.u = ((unsigned)h) << 16;
    return c.f;
}

// async global->LDS, 16B per lane; LDS dest = wave-uniform base + lane*16,
// global source address is PER-LANE (enables pre-swizzled-source T21 layouts)
__device__ __forceinline__ void gload_lds16(const u16* g, u16* l) {
    __builtin_amdgcn_global_load_lds(
        (const __attribute__((address_space(1))) unsigned int*)(g),
        (__attribute__((address_space(3))) unsigned int*)(l),
        16, 0, 0);
}

// ---------------------------------------------------------------------------
// k_pre: merged pre-processing (UNCHANGED from round 3 — verified).
//   blocks [0,768)     : lnproj — 16 i x 8 s per block, DMA staging,
//                        reg-LN, split-precision bf16 MFMA projection
//   blocks [768,896)   : Wo f32 -> bf16 k'-permuted
//   blocks [896,1472)  : norm matrix
// ---------------------------------------------------------------------------
__global__ __launch_bounds__(256) void k_pre(
    const float* __restrict__ M, const float* __restrict__ mask,
    const float* __restrict__ gamma, const float* __restrict__ beta,
    const float* __restrict__ Wa, const float* __restrict__ ba,
    const float* __restrict__ Wb, const float* __restrict__ bb,
    const float* __restrict__ Wo,
    u16* __restrict__ leftT, u16* __restrict__ rightT,
    float* __restrict__ normMat, u16* __restrict__ WoB)
{
    __shared__ __align__(16) char sm[52480];
    const int b = blockIdx.x, t = threadIdx.x;

    if (b < 768) {
        const int sC = b / 24, iC = b % 24;
        const int i0 = iC * 16, s0 = sC * 8;

        u16*   hiP   = (u16*)sm;
        u16*   loP   = (u16*)sm + 8192;
        u16*   WP    = (u16*)(sm + 32768);
        float* mkP   = (float*)(sm + 51200);
        float* biasP = (float*)(sm + 51712);
        float* glP   = (float*)(sm + 51968);
        float* blP   = (float*)(sm + 52224);

        const int wv = t >> 6, ln = t & 63;
        const int quad = ln >> 4, l16 = ln & 15;

        {
            const int rl = ln >> 4, c = ln & 15;
            #pragma unroll
            for (int q = 0; q < 8; ++q) {
                int rbase = wv * 32 + q * 4;
                int r   = rbase + rl;
                int xsw = (r & 3) << 1;
                const float* src = M + ((long)(s0 + (r & 7)) * NRES + (i0 + (r >> 3))) * NF
                                     + ((c ^ xsw) << 2);
                gload_lds16((const u16*)src, (u16*)sm + rbase * 128);
            }
        }
        {
            const int side = t >> 7, p = (t >> 2) & 31, qq = t & 3;
            const float* Wg = (side ? Wb : Wa) + p * 64 + qq * 16;
            u16x8 h[2], l[2];
            #pragma unroll
            for (int u = 0; u < 4; ++u) {
                f32x4 w4 = *(const f32x4*)(Wg + u * 4);
                #pragma unroll
                for (int e = 0; e < 4; ++e) {
                    u16 hb = f2b(w4[e]);
                    h[u >> 1][(u & 1) * 4 + e] = hb;
                    l[u >> 1][(u & 1) * 4 + e] = f2b(w4[e] - b2f(hb));
                }
            }
            int hbase = ((side * 2 + 0) * 32 + p) * 72 + qq * 16;
            int lbase = ((side * 2 + 1) * 32 + p) * 72 + qq * 16;
            *(u16x8*)(WP + hbase)     = h[0];
            *(u16x8*)(WP + hbase + 8) = h[1];
            *(u16x8*)(WP + lbase)     = l[0];
            *(u16x8*)(WP + lbase + 8) = l[1];
        }
        if (t < 128) mkP[t] = mask[(long)(s0 + (t & 7)) * NRES + i0 + (t >> 3)];
        if (t < 64) { glP[t] = gamma[t]; blP[t] = beta[t];
                      biasP[t] = (t < 32) ? ba[t] : bb[t - 32]; }
        __syncthreads();

        const int r = t >> 1, half = t & 1;
        const int xsw = (r & 3) << 1, psw = r & 3;
        f32x4 v[8];
        {
            const float* raw = (const float*)sm + r * 64;
            #pragma unroll
            for (int e = 0; e < 8; ++e)
                v[e] = *(const f32x4*)(raw + (((half * 8 + e) ^ xsw) << 2));
        }
        float sum = 0.f, sq = 0.f;
        #pragma unroll
        for (int e = 0; e < 8; ++e)
            #pragma unroll
            for (int j = 0; j < 4; ++j) { float x = v[e][j]; sum += x; sq += x * x; }
        sum += __shfl_xor(sum, 1); sq += __shfl_xor(sq, 1);
        float mu  = sum * (1.f / 64.f);
        float var = sq * (1.f / 64.f) - mu * mu;
        float rs  = rsqrtf(var + 1e-5f);
        #pragma unroll
        for (int e = 0; e < 8; ++e) {
            int og = half * 8 + e;
            f32x4 g4 = *(const f32x4*)(glP + og * 4);
            f32x4 b4 = *(const f32x4*)(blP + og * 4);
            #pragma unroll
            for (int j = 0; j < 4; ++j) v[e][j] = (v[e][j] - mu) * rs * g4[j] + b4[j];
        }
        __syncthreads();

        #pragma unroll
        for (int d = 0; d < 4; ++d) {
            u16x8 h8, l8;
            #pragma unroll
            for (int j = 0; j < 4; ++j) {
                u16 hb = f2b(v[2 * d][j]);
                h8[j] = hb; l8[j] = f2b(v[2 * d][j] - b2f(hb));
                u16 hb2 = f2b(v[2 * d + 1][j]);
                h8[4 + j] = hb2; l8[4 + j] = f2b(v[2 * d + 1][j] - b2f(hb2));
            }
            int q = (half * 4 + d) ^ psw;
            *(u16x8*)(hiP + r * 64 + q * 8) = h8;
            *(u16x8*)(loP + r * 64 + q * 8) = l8;
        }
        __syncthreads();

        const int wbase = wv * 32;
        f32x4 acc[2][4] = {};
        #pragma unroll
        for (int k = 0; k < 2; ++k) {
            u16x8 ah[2], al[2];
            #pragma unroll
            for (int rt = 0; rt < 2; ++rt) {
                int row = wbase + rt * 16 + l16;
                int gk  = (quad + k * 4) ^ (row & 3);
                ah[rt] = *(const u16x8*)(hiP + row * 64 + gk * 8);
                al[rt] = *(const u16x8*)(loP + row * 64 + gk * 8);
            }
            #pragma unroll
            for (int pt = 0; pt < 4; ++pt) {
                int side = pt >> 1, ph = pt & 1;
                int hrow = ((side * 2 + 0) * 32 + ph * 16 + l16) * 72 + (quad + k * 4) * 8;
                int lrow = ((side * 2 + 1) * 32 + ph * 16 + l16) * 72 + (quad + k * 4) * 8;
                u16x8 bh = *(const u16x8*)(WP + hrow);
                u16x8 bl = *(const u16x8*)(WP + lrow);
                #pragma unroll
                for (int rt = 0; rt < 2; ++rt) {
                    acc[rt][pt] = __builtin_amdgcn_mfma_f32_16x16x32_bf16(
                        (s16x8)ah[rt], (s16x8)bh, acc[rt][pt], 0, 0, 0);
                    acc[rt][pt] = __builtin_amdgcn_mfma_f32_16x16x32_bf16(
                        (s16x8)al[rt], (s16x8)bh, acc[rt][pt], 0, 0, 0);
                    acc[rt][pt] = __builtin_amdgcn_mfma_f32_16x16x32_bf16(
                        (s16x8)ah[rt], (s16x8)bl, acc[rt][pt], 0, 0, 0);
                }
            }
        }

        #pragma unroll
        for (int rt = 0; rt < 2; ++rt) {
            int rowb = wbase + rt * 16 + quad * 4;
            f32x4 mk4 = *(const f32x4*)(mkP + rowb);
            int ii = rowb >> 3, sb = rowb & 7;
            #pragma unroll
            for (int pt = 0; pt < 4; ++pt) {
                int side = pt >> 1, p = (pt & 1) * 16 + l16;
                float bv = biasP[side * 32 + p];
                u16x4 ov;
                #pragma unroll
                for (int rg = 0; rg < 4; ++rg)
                    ov[rg] = f2b((acc[rt][pt][rg] + bv) * mk4[rg]);
                u16* dst = (side ? rightT : leftT)
                         + ((long)(i0 + ii) * NP + p) * NSEQ + s0 + sb;
                *(u16x4*)dst = ov;
            }
        }

    } else if (b < 896) {
        int idx = (b - 768) * 256 + t;
        int o   = idx >> 8;
        int kp  = (idx & 255) << 2;
        int l16 = (kp >> 2) & 15;
        int ntb = (kp >> 6) & 1;
        int qd  = (kp >> 7) & 3;
        int mtb = (kp >> 9) & 1;
        const float* src = Wo + o * 1024 + (mtb * 16 + qd * 4) * 32 + ntb * 16 + l16;
        u16x4 w;
        #pragma unroll
        for (int rg = 0; rg < 4; ++rg) w[rg] = f2b(src[rg * 32]);
        *(u16x4*)(WoB + o * 1024 + kp) = w;

    } else {
        float (*mi)[17] = (float (*)[17])sm;
        float (*mj)[17] = (float (*)[17])(sm + 17408);
        const int bn = b - 896;
        const int iB = (bn / 24) * 16, jB = (bn % 24) * 16;
        #pragma unroll
        for (int it = 0; it < 16; ++it) {
            int ss = it * 16 + (t >> 4);
            int c  = t & 15;
            mi[ss][c] = mask[(long)ss * NRES + iB + c];
            mj[ss][c] = mask[(long)ss * NRES + jB + c];
        }
        __syncthreads();
        const int ti = t >> 4, tj = t & 15;
        float acc = 0.f;
        for (int ss = 0; ss < 256; ++ss) acc += mi[ss][ti] * mj[ss][tj];
        normMat[(long)(iB + ti) * NRES + jB + tj] = acc;
    }
}

// ---------------------------------------------------------------------------
// k_main v3: 256x128 tile, 8 waves.
//  Stage 1: TRIPLE-buffered async staging, ONE barrier per K-step:
//    vmcnt(3) -> s_barrier -> STAGE(kt+2 into buf (kt+2)%3) -> ds_read+MFMA.
//    Write target (kt+2)%3 == buffer read at kt-1, protected by the barrier.
//    9 loads in flight; waves drift within an iteration so LDS-read bursts
//    overlap MFMA bursts across waves.
//  Stage 2: split-k: 8 waves = 4 o-blocks x 2 k-halves. Each wave reads
//    32 pairs x 512 k of Os (Os LDS traffic 8x -> 4x) + 32 o x 512 k of Wo
//    (L2 traffic unchanged). f32 write-then-add reduction in LDS (stride 132).
//  LDS: 3 x 24 KB staging = 72 KB; Os overlay 64 KB; zs overlay 16.9 KB.
// ---------------------------------------------------------------------------
__global__ __launch_bounds__(512, 4) void k_main(
    const u16* __restrict__ leftT, const u16* __restrict__ rightT,
    const float* __restrict__ normMat,
    const u16* __restrict__ WoB, const float* __restrict__ bo,
    const float* __restrict__ Zraw, float* __restrict__ out)
{
    // buf b (u16 idx): A [256x32] at b*12288, B [128x32] at b*12288+8192
    // Os overlay [32 pairs][1024 k'] = u16 [0, 32768); zs f32[32][132] overlay
    __shared__ __align__(16) u16 smem[36864];

    const int t    = threadIdx.x;
    const int wave = t >> 6, lane = t & 63;
    const int quad = lane >> 4, l16 = lane & 15;
    const int wr = wave >> 1, wc = wave & 1;

    const int bid = blockIdx.x;
    const int r_  = bid >> 3;
    const int bx  = r_ / 12;
    const int by  = (bid & 7) * 12 + (r_ % 12);
    const int icBase = bx * 256;
    const int jdBase = by * 128;

    const int srow = lane >> 2;
    const int g8   = ((lane & 3) ^ ((srow >> 1) & 3)) * 8;

    f32x4 acc[4][4] = {};

    const u16* aSrc0 = leftT  + (icBase + wave * 32 + srow) * NSEQ + g8;
    const u16* aSrc1 = aSrc0 + 16 * NSEQ;
    const u16* bSrc  = rightT + (jdBase + wave * 16 + srow) * NSEQ + g8;

    #define STAGE(bb, k0) do {                                                   \
        gload_lds16(aSrc0 + (k0), &smem[(bb) * 12288 + wave * 1024]);            \
        gload_lds16(aSrc1 + (k0), &smem[(bb) * 12288 + wave * 1024 + 512]);      \
        gload_lds16(bSrc  + (k0), &smem[(bb) * 12288 + 8192 + wave * 512]);      \
    } while (0)

    STAGE(0, 0);
    STAGE(1, 32);                                    // 6 loads in flight

    #pragma unroll
    for (int kt = 0; kt < 8; ++kt) {
        if (kt < 7) asm volatile("s_waitcnt vmcnt(3)" ::: "memory");  // kt's 3 landed
        else        asm volatile("s_waitcnt vmcnt(0)" ::: "memory");
        __builtin_amdgcn_s_barrier();                // kt data visible to all
        __builtin_amdgcn_sched_barrier(0);
        if (kt < 6) STAGE((kt + 2) % 3, (kt + 2) * 32);   // overwrites buf read at kt-1

        const int bb = kt % 3;                       // compile-time (full unroll)
        const int gx = (quad ^ ((l16 >> 1) & 3)) * 8;
        u16x8 af[4], bf[4];
        const u16* Ab = &smem[bb * 12288 + (wr * 64 + l16) * 32 + gx];
        const u16* Bb = &smem[bb * 12288 + 8192 + (wc * 64 + l16) * 32 + gx];
        #pragma unroll
        for (int mt = 0; mt < 4; ++mt) af[mt] = *(const u16x8*)(Ab + mt * 512);
        #pragma unroll
        for (int nt = 0; nt < 4; ++nt) bf[nt] = *(const u16x8*)(Bb + nt * 512);

        __builtin_amdgcn_s_setprio(1);
        #pragma unroll
        for (int mt = 0; mt < 4; ++mt)
            #pragma unroll
            for (int nt = 0; nt < 4; ++nt)
                acc[mt][nt] = __builtin_amdgcn_mfma_f32_16x16x32_bf16(
                    (s16x8)af[mt], (s16x8)bf[nt], acc[mt][nt], 0, 0, 0);
        __builtin_amdgcn_s_setprio(0);
        // no trailing barrier: next iteration's top barrier protects reuse
    }
    #undef STAGE
    __syncthreads();                                 // all frag reads done

    // ---- O tile -> Os overlay [pair][k'], swizzled (unchanged layout) ------
    #pragma unroll
    for (int mt = 0; mt < 4; ++mt) {
        #pragma unroll
        for (int nt = 0; nt < 4; ++nt) {
            int pair = (wr * 2 + (mt >> 1)) * 4 + wc * 2 + (nt >> 1);
            int kp   = l16 * 4 + (nt & 1) * 64 + quad * 128 + (mt & 1) * 512;
            int ks   = kp ^ (quad << 4) ^ ((pair & 7) << 3);
            u16x4 wv;
            #pragma unroll
            for (int rg = 0; rg < 4; ++rg) wv[rg] = f2b(acc[mt][nt][rg]);
            *(u16x4*)&smem[pair * 1024 + ks] = wv;
        }
    }
    __syncthreads();

    // ---- stage 2: split-k. wave = (kh = wave>>2) x (oh = wave&3) -----------
    // wave: pairs 0..31 (2 tiles) x o [oh*32, +32) (2 tiles) x k' [kh*512,+512)
    f32x4 acc2[2][2] = {};
    const int oh = wave & 3, kh = wave >> 2;
    const int ob = oh * 32;
    const int pxor = (l16 & 7) << 3;
    const u16* wp0 = WoB + (long)(ob + l16) * 1024 + kh * 512 + quad * 8;
    const u16* wp1 = wp0 + 16 * 1024;
    const u16* os0 = &smem[l16 * 1024];
    const u16* os1 = &smem[(16 + l16) * 1024];
    #pragma unroll 8
    for (int kk = 0; kk < 16; ++kk) {
        int kp = kh * 512 + kk * 32 + quad * 8;
        int ks = kp ^ (((kp >> 7) & 3) << 4) ^ pxor;
        u16x8 a0 = *(const u16x8*)(os0 + ks);
        u16x8 a1 = *(const u16x8*)(os1 + ks);
        u16x8 b0 = *(const u16x8*)(wp0 + kk * 32);
        u16x8 b1 = *(const u16x8*)(wp1 + kk * 32);
        __builtin_amdgcn_s_setprio(1);
        acc2[0][0] = __builtin_amdgcn_mfma_f32_16x16x32_bf16((s16x8)a0, (s16x8)b0, acc2[0][0], 0, 0, 0);
        acc2[0][1] = __builtin_amdgcn_mfma_f32_16x16x32_bf16((s16x8)a0, (s16x8)b1, acc2[0][1], 0, 0, 0);
        acc2[1][0] = __builtin_amdgcn_mfma_f32_16x16x32_bf16((s16x8)a1, (s16x8)b0, acc2[1][0], 0, 0, 0);
        acc2[1][1] = __builtin_amdgcn_mfma_f32_16x16x32_bf16((s16x8)a1, (s16x8)b1, acc2[1][1], 0, 0, 0);
        __builtin_amdgcn_s_setprio(0);
    }
    __syncthreads();                                 // all Os reads done

    // ---- k-half reduction into zs f32[32][132] -----------------------------
    float* zs = (float*)smem;
    if (kh == 0) {
        #pragma unroll
        for (int ph = 0; ph < 2; ++ph)
            #pragma unroll
            for (int n2 = 0; n2 < 2; ++n2)
                #pragma unroll
                for (int rg = 0; rg < 4; ++rg)
                    zs[(ph * 16 + quad * 4 + rg) * 132 + ob + n2 * 16 + l16]
                        = acc2[ph][n2][rg];
    }
    __syncthreads();
    if (kh == 1) {
        #pragma unroll
        for (int ph = 0; ph < 2; ++ph)
            #pragma unroll
            for (int n2 = 0; n2 < 2; ++n2)
                #pragma unroll
                for (int rg = 0; rg < 4; ++rg)
                    zs[(ph * 16 + quad * 4 + rg) * 132 + ob + n2 * 16 + l16]
                        += acc2[ph][n2][rg];
    }
    __syncthreads();

    // ---- epilogue: one wave stores 2 KB contiguous -------------------------
    const int i0 = bx * 8, j0 = by * 4;
    const int pr = t >> 4, o0 = (t & 15) * 8;
    const int i = i0 + (pr >> 2), j = j0 + (pr & 3);
    const float rn = 1.f / (0.001f + normMat[i * NRES + j]);
    const long base = ((long)(i * NRES + j)) * NO + o0;
    f32x4 z0  = *(const f32x4*)&zs[pr * 132 + o0];
    f32x4 z1  = *(const f32x4*)&zs[pr * 132 + o0 + 4];
    f32x4 zr0 = *(const f32x4*)(Zraw + base);
    f32x4 zr1 = *(const f32x4*)(Zraw + base + 4);
    f32x4 bv0 = *(const f32x4*)(bo + o0);
    f32x4 bv1 = *(const f32x4*)(bo + o0 + 4);
    f32x4 r0, r1;
    #pragma unroll
    for (int e = 0; e < 4; ++e) r0[e] = (z0[e] + bv0[e]) * rn + zr0[e];
    #pragma unroll
    for (int e = 0; e < 4; ++e) r1[e] = (z1[e] + bv1[e]) * rn + zr1[e];
    *(f32x4*)(out + base)     = r0;
    *(f32x4*)(out + base + 4) = r1;
}

extern "C" void kernel_launch(void* const* d_in, const int* in_sizes, int n_in,
                              void* d_out, int out_size, void* d_ws, size_t ws_size,
                              hipStream_t stream)
{
    const float* M     = (const float*)d_in[0];
    const float* mask  = (const float*)d_in[1];
    const float* Zraw  = (const float*)d_in[2];
    const float* gamma = (const float*)d_in[3];
    const float* beta  = (const float*)d_in[4];
    const float* Wa    = (const float*)d_in[5];
    const float* ba    = (const float*)d_in[6];
    const float* Wb    = (const float*)d_in[7];
    const float* bb    = (const float*)d_in[8];
    const float* Wo    = (const float*)d_in[9];
    const float* bo    = (const float*)d_in[10];
    float* out = (float*)d_out;

    char* ws = (char*)d_ws;
    u16*   leftT   = (u16*)ws;                      // 12288 x 256 bf16
    u16*   rightT  = (u16*)(ws + 6291456);
    float* normMat = (float*)(ws + 12582912);       // 384x384 f32
    u16*   WoB     = (u16*)(ws + 13172736);         // 128x1024 bf16 (k'-permuted)

    k_pre<<<dim3(1472), dim3(256), 0, stream>>>(M, mask, gamma, beta,
                                                Wa, ba, Wb, bb, Wo,
                                                leftT, rightT, normMat, WoB);
    k_main<<<dim3(4608), dim3(512), 0, stream>>>(leftT, rightT, normMat,
                                                 WoB, bo, Zraw, out);
}